// Round 20
// baseline (155.874 us; speedup 1.0000x reference)
//
#include <hip/hip_runtime.h>
#include <hip/hip_bf16.h>

#define BATCH 32
#define CH    256
#define HWPX  3136   // 56*56
#define WIDTH 56
#define NK    16
#define NSLAB 28     // kpmat pixel slabs per batch (112 px each)
#define NSUB  4      // kkvec channel split
#define WGTS  56     // wgt row stride in USHORT (bf16; 112B = 7x uint4)
#define EPSV  1e-5f

__device__ __forceinline__ unsigned pk_bf2(float a, float b) {
    __hip_bfloat16 ha = __float2bfloat16(a), hb = __float2bfloat16(b);
    unsigned short ua = *reinterpret_cast<unsigned short*>(&ha);
    unsigned short ub = *reinterpret_cast<unsigned short*>(&hb);
    return ((unsigned)ub << 16) | ua;
}
__device__ __forceinline__ unsigned short bf16u(float f) {
    __hip_bfloat16 h = __float2bfloat16(f);
    return *reinterpret_cast<unsigned short*>(&h);
}
__device__ __forceinline__ float up_lo(unsigned v) { return __uint_as_float(v << 16); }
__device__ __forceinline__ float up_hi(unsigned v) { return __uint_as_float(v & 0xffff0000u); }

// ---------------------------------------------------------------------------
// Kernel 1: K-partials via 1-wave tile-transpose blocks.
// R19 profile: old kkvec stuck ~55us in the contiguous-512B-load regime
// (~2TB/s family ceiling, R13-R16). kpmat's channel-scattered float4 loads
// (64 lines/instr) run ~2x faster. This kernel stages a 64ch x 64px tile with
// THAT pattern (lane=channel, 16 scattered float4s), then lane=pixel computes
// K over the 64 staged channels (kw via uniform s_loads). 1-wave blocks ->
// barrier is cheap; LDS 16.6KB -> ~9 blocks/CU interleave stage/compute.
// Unlike R17's fused 256-thread 3-phase kernel (2 blocks/CU, serialized).
// ---------------------------------------------------------------------------
__global__ __launch_bounds__(64) void kkvec(
    const float* __restrict__ x,
    const float* __restrict__ gamma, const float* __restrict__ beta,
    const float* __restrict__ mean,  const float* __restrict__ var,
    const float* __restrict__ kw,    unsigned short* __restrict__ Kpart)
{
    const int blk = blockIdx.x;                 // 0..6271
    const int sub = blk / 1568;                 // 0..3, block-uniform
    const int rem = blk - sub * 1568;
    const int b   = rem / 49;
    const int t   = rem - b * 49;
    const int n0  = t * 64;
    const int lane = threadIdx.x;               // 0..63

    __shared__ float s_x[64 * 65];              // 16,640 B (pitch 65: stage
                                                // b128 canonical; reads 2-way)

    // ---- stage: lane = local channel; 16 scattered float4 loads ----
    {
        const int ch = sub * 64 + lane;
        const float sc = gamma[ch] * rsqrtf(var[ch] + EPSV);
        const float sh = fmaf(-mean[ch], sc, beta[ch]);
        const float4* xr = (const float4*)(x + ((size_t)b * CH + ch) * HWPX + n0);
        float* dst = s_x + lane * 65;
#pragma unroll
        for (int j = 0; j < 16; ++j) {
            const float4 v = xr[j];
            dst[4*j+0] = fmaf(v.x, sc, sh);
            dst[4*j+1] = fmaf(v.y, sc, sh);
            dst[4*j+2] = fmaf(v.z, sc, sh);
            dst[4*j+3] = fmaf(v.w, sc, sh);
        }
    }
    __syncthreads();

    // ---- K: lane = pixel; sum over 64 channels; kw uniform -> s_load ----
    {
        const int p = lane;
        float acc[NK];
#pragma unroll
        for (int k = 0; k < NK; ++k) acc[k] = 0.f;
#pragma unroll 4
        for (int c0 = 0; c0 < 64; c0 += 4) {
            const float xv0 = s_x[(c0+0)*65 + p];   // consecutive lanes/banks
            const float xv1 = s_x[(c0+1)*65 + p];
            const float xv2 = s_x[(c0+2)*65 + p];
            const float xv3 = s_x[(c0+3)*65 + p];
#pragma unroll
            for (int k = 0; k < NK; ++k) {
                const float4 k4 = *(const float4*)(kw + k * CH + sub * 64 + c0);
                acc[k] = fmaf(xv0, k4.x, acc[k]);
                acc[k] = fmaf(xv1, k4.y, acc[k]);
                acc[k] = fmaf(xv2, k4.z, acc[k]);
                acc[k] = fmaf(xv3, k4.w, acc[k]);
            }
        }
        // bf16 pack: 16 k = 32B/lane contiguous (2KB per wave)
        unsigned short* op = Kpart +
            ((size_t)sub * BATCH * HWPX + (size_t)b * HWPX + n0 + p) * NK;
        uint4* op4 = (uint4*)op;
        op4[0] = make_uint4(pk_bf2(acc[0],  acc[1]),  pk_bf2(acc[2],  acc[3]),
                            pk_bf2(acc[4],  acc[5]),  pk_bf2(acc[6],  acc[7]));
        op4[1] = make_uint4(pk_bf2(acc[8],  acc[9]),  pk_bf2(acc[10], acc[11]),
                            pk_bf2(acc[12], acc[13]), pk_bf2(acc[14], acc[15]));
    }
}

// ---------------------------------------------------------------------------
// Kernel 1b: Kbuf(fp32) = sum of 4 bf16 Kpart planes (unpack = exact <<16).
// ---------------------------------------------------------------------------
__global__ __launch_bounds__(256) void ksum(
    const unsigned short* __restrict__ Kpart, float* __restrict__ Kbuf)
{
    const int i = blockIdx.x * 256 + threadIdx.x;   // 0..401407 float4 jobs
    const uint2* p = (const uint2*)Kpart;           // 4 bf16 per uint2
    float4 s = make_float4(0.f, 0.f, 0.f, 0.f);
#pragma unroll
    for (int s2 = 0; s2 < NSUB; ++s2) {
        const uint2 v = p[(size_t)s2 * 401408 + i];
        s.x += up_lo(v.x); s.y += up_hi(v.x);
        s.z += up_lo(v.y); s.w += up_hi(v.y);
    }
    ((float4*)Kbuf)[i] = s;
}

// ---------------------------------------------------------------------------
// Kernel 2: P_part[b,nb,c,k] = sum_{n in 112-px slab} BN(x[b,c,n]) * K[b,n,k]
// ---------------------------------------------------------------------------
__global__ __launch_bounds__(256) void kpmat(
    const float* __restrict__ x,
    const float* __restrict__ gamma, const float* __restrict__ beta,
    const float* __restrict__ mean,  const float* __restrict__ var,
    const float* __restrict__ Kbuf,  float* __restrict__ Pp)
{
    const int b  = blockIdx.x / NSLAB;
    const int nb = blockIdx.x % NSLAB;
    const int n0 = nb * 112;
    const int c  = threadIdx.x;

    const float sc = gamma[c] * rsqrtf(var[c] + EPSV);
    const float sh = fmaf(-mean[c], sc, beta[c]);

    const float4* xr = (const float4*)(x + ((size_t)b * CH + c) * HWPX + n0);
    const float*  Kp = Kbuf + ((size_t)b * HWPX + n0) * NK;

    float acc[NK];
#pragma unroll
    for (int k = 0; k < NK; ++k) acc[k] = 0.f;

#pragma unroll 4
    for (int j = 0; j < 28; ++j) {
        const float4 xv = xr[j];
        float v[4];
        v[0] = fmaf(xv.x, sc, sh); v[1] = fmaf(xv.y, sc, sh);
        v[2] = fmaf(xv.z, sc, sh); v[3] = fmaf(xv.w, sc, sh);
#pragma unroll
        for (int d = 0; d < 4; ++d) {
            const float vd = v[d];
#pragma unroll
            for (int kq = 0; kq < 4; ++kq) {
                const float4 kv = *(const float4*)(Kp + ((j*4 + d) * NK) + kq*4); // uniform
                acc[kq*4+0] = fmaf(vd, kv.x, acc[kq*4+0]);
                acc[kq*4+1] = fmaf(vd, kv.y, acc[kq*4+1]);
                acc[kq*4+2] = fmaf(vd, kv.z, acc[kq*4+2]);
                acc[kq*4+3] = fmaf(vd, kv.w, acc[kq*4+3]);
            }
        }
    }
    float4* op = (float4*)(Pp + (((size_t)b * NSLAB + nb) * CH + c) * NK);
#pragma unroll
    for (int kq = 0; kq < 4; ++kq)
        op[kq] = make_float4(acc[kq*4+0], acc[kq*4+1], acc[kq*4+2], acc[kq*4+3]);
}

// ---------------------------------------------------------------------------
// Kernel 2b: reduce slab partials Pp[b][28][CH*NK] -> P[b][CH*NK]
// ---------------------------------------------------------------------------
__global__ __launch_bounds__(256) void kpred(
    const float* __restrict__ Pp, float* __restrict__ P)
{
    const int idx = blockIdx.x * 256 + threadIdx.x;   // 32*4096 total
    const int b = idx >> 12;
    const int e = idx & 4095;
    const float* p = Pp + (size_t)b * NSLAB * 4096 + e;
    float s = 0.f;
#pragma unroll
    for (int nb = 0; nb < NSLAB; ++nb) s += p[(size_t)nb * 4096];
    P[idx] = s;
}

// ---------------------------------------------------------------------------
// Kernel 3: S = q_w @ P; attn = softmax(S/512); wgt = attn @ bank (bf16 out,
// stride-56 ushort rows -> 7 aligned uint4 loads in kconv).
// ---------------------------------------------------------------------------
__global__ __launch_bounds__(256) void ksoft(
    const float* __restrict__ P, const float* __restrict__ qw,
    const float* __restrict__ bank, unsigned short* __restrict__ wgt)
{
    const int b  = blockIdx.x >> 3;
    const int cb = blockIdx.x & 7;
    const int tid = threadIdx.x;

    __shared__ float s_P[CH * NK];       // full P[b] (16 KB)
    __shared__ float s_red[32 * 8 * NK]; // partial S (16 KB)
    __shared__ float s_S[32 * NK];
    __shared__ float s_attn[32 * NK];

    for (int idx = tid; idx < CH * NK; idx += 256)
        s_P[idx] = P[(size_t)b * CH * NK + idx];
    __syncthreads();

    const int c_l = tid & 31, sub = tid >> 5;
    const int c = cb * 32 + c_l;
    float a[NK];
#pragma unroll
    for (int k = 0; k < NK; ++k) a[k] = 0.f;
    const float* qrow = qw + (size_t)c * CH + sub * 32;
    for (int j = 0; j < 32; ++j) {
        const float qv = qrow[j];
        const float4* p4 = (const float4*)&s_P[(sub * 32 + j) * NK];
#pragma unroll
        for (int kq = 0; kq < 4; ++kq) {
            const float4 pv = p4[kq];
            a[kq*4+0] = fmaf(qv, pv.x, a[kq*4+0]);
            a[kq*4+1] = fmaf(qv, pv.y, a[kq*4+1]);
            a[kq*4+2] = fmaf(qv, pv.z, a[kq*4+2]);
            a[kq*4+3] = fmaf(qv, pv.w, a[kq*4+3]);
        }
    }
#pragma unroll
    for (int kq = 0; kq < 4; ++kq)
        *(float4*)&s_red[(c_l * 8 + sub) * NK + kq*4] =
            make_float4(a[kq*4+0], a[kq*4+1], a[kq*4+2], a[kq*4+3]);
    __syncthreads();

    for (int idx = tid; idx < 32 * NK; idx += 256) {
        const int cl = idx >> 4, k = idx & 15;
        float s = 0.f;
#pragma unroll
        for (int s2 = 0; s2 < 8; ++s2) s += s_red[(cl * 8 + s2) * NK + k];
        s_S[idx] = s * (1.f / 512.f);
    }
    __syncthreads();

    if (tid < 32) {
        float l[NK];
#pragma unroll
        for (int k = 0; k < NK; ++k) l[k] = s_S[tid * NK + k];
        float m = l[0];
#pragma unroll
        for (int k = 1; k < NK; ++k) m = fmaxf(m, l[k]);
        float sum = 0.f;
#pragma unroll
        for (int k = 0; k < NK; ++k) { l[k] = __expf(l[k] - m); sum += l[k]; }
        const float inv = 1.f / sum;
#pragma unroll
        for (int k = 0; k < NK; ++k) s_attn[tid * NK + k] = l[k] * inv;
    }
    __syncthreads();

    for (int idx = tid; idx < 32 * 49; idx += 256) {
        const int cl = idx / 49, e = idx - cl * 49;
        float wv = 0.f;
#pragma unroll
        for (int k = 0; k < NK; ++k)
            wv = fmaf(s_attn[cl * NK + k], bank[k * 49 + e], wv);
        wgt[((size_t)b * CH + cb * 32 + cl) * WGTS + e] = bf16u(wv);
    }
}

// ---------------------------------------------------------------------------
// Kernel 4: depthwise 7x7 conv — zero-LDS shuffle-halo (R9 slot schedule).
// R19 profile: VGPR 120 -> 4 waves/SIMD cap, VALUBusy 44%, latency-bound.
// R20: (a) weights packed bf16 (28 uints vs 52 fp32 VGPRs; unpack = 1 bit-op
// per use); (b) y-QUARTERS (ho = h*14, all ==0 mod 7; 21-iter loop = 3x7
// keeps slot indices static; j=20 accumulates only never-stored slots).
// VGPR ~90 -> 5 waves/SIMD; grid 2048 supplies 8 blocks/CU.
// ---------------------------------------------------------------------------
__global__ __launch_bounds__(256) void kconv(
    const float* __restrict__ x, const unsigned short* __restrict__ wgt,
    const float* __restrict__ bias, float* __restrict__ out)
{
    const int t  = threadIdx.x;          // 0..255
    const int pl = t >> 4;               // 0..15 local plane
    const int q  = t & 15;               // 0..15 strip slot (14 valid)
    const int qc = q < 14 ? q : 13;      // clamped col chunk for idle lanes
    const int h  = blockIdx.x & 3;       // y-quarter
    const int plane = (blockIdx.x >> 2) * 16 + pl;
    const int ho = h * 14;               // 0,14,28,42 — all ==0 mod 7
    const bool qlo = (q == 0), qhi = (q >= 13);
    const float bv = bias[plane & 255];

    // 49 bf16 weights in 25 packed uints (7 aligned uint4 loads; 112B rows)
    unsigned wu[28];
    const uint4* wp4 = (const uint4*)(wgt + (size_t)plane * WGTS);
#pragma unroll
    for (int i = 0; i < 7; ++i) {
        const uint4 v = wp4[i];
        wu[4*i+0] = v.x; wu[4*i+1] = v.y; wu[4*i+2] = v.z; wu[4*i+3] = v.w;
    }
#define WTAP(idx) __uint_as_float(((idx) & 1) ? (wu[(idx)>>1] & 0xffff0000u) \
                                              : (wu[(idx)>>1] << 16))

    const float* xrow = x   + (size_t)plane * HWPX + 4 * qc;
    float*       orow = out + (size_t)plane * HWPX + 4 * qc;

    float a[7][4];
#pragma unroll
    for (int i = 0; i < 7; ++i)
#pragma unroll
        for (int ix = 0; ix < 4; ++ix) a[i][ix] = bv;

    const float4 z4 = make_float4(0.f, 0.f, 0.f, 0.f);
    int ir0 = ho - 3;
    float4 vc = (0 <= ir0 && ir0 < 56) ? *(const float4*)(xrow + ir0 * WIDTH) : z4;

#pragma unroll 7
    for (int j = 0; j < 21; ++j) {
        const int snew = j % 7;                  // static under unroll 7
#pragma unroll
        for (int ix = 0; ix < 4; ++ix) a[snew][ix] = bv;

        const int irn = ho - 3 + j + 1;
        float4 vn = (0 <= irn && irn < 56 && j + 1 < 21)
                        ? *(const float4*)(xrow + irn * WIDTH) : z4;

        float rr1 = __shfl_up(vc.y, 1), rr2 = __shfl_up(vc.z, 1), rr3 = __shfl_up(vc.w, 1);
        float rr8 = __shfl_down(vc.x, 1), rr9 = __shfl_down(vc.y, 1), rr10 = __shfl_down(vc.z, 1);
        float rr[11];
        rr[1] = qlo ? 0.f : rr1;  rr[2] = qlo ? 0.f : rr2;  rr[3] = qlo ? 0.f : rr3;
        rr[4] = vc.x; rr[5] = vc.y; rr[6] = vc.z; rr[7] = vc.w;
        rr[8] = qhi ? 0.f : rr8;  rr[9] = qhi ? 0.f : rr9;  rr[10] = qhi ? 0.f : rr10;

#pragma unroll
        for (int i = 0; i < 7; ++i) {
            const int ky = 6 - i;
            const int s  = (j + i + 1) % 7;      // static (j%7 known by unroll)
#pragma unroll
            for (int kx = 0; kx < 7; ++kx) {
                const float wk = WTAP(ky * 7 + kx);
#pragma unroll
                for (int ix = 0; ix < 4; ++ix)
                    a[s][ix] = fmaf(wk, rr[ix + kx + 1], a[s][ix]);
            }
        }

        if (j >= 6 && j < 20) {                  // out row o = ho+j-6 done
            const int o  = ho + j - 6;
            const int sd = (j + 1) % 7;          // static; next iter resets it
            if (q < 14)
                *(float4*)(orow + o * WIDTH) =
                    make_float4(a[sd][0], a[sd][1], a[sd][2], a[sd][3]);
        }
        vc = vn;
    }
#undef WTAP
}

// ---------------------------------------------------------------------------
extern "C" void kernel_launch(void* const* d_in, const int* in_sizes, int n_in,
                              void* d_out, int out_size, void* d_ws, size_t ws_size,
                              hipStream_t stream)
{
    const float* x     = (const float*)d_in[0];
    const float* gamma = (const float*)d_in[1];
    const float* beta  = (const float*)d_in[2];
    const float* mean  = (const float*)d_in[3];
    const float* var   = (const float*)d_in[4];
    const float* qw    = (const float*)d_in[5];
    const float* kw    = (const float*)d_in[6];
    const float* bank  = (const float*)d_in[7];
    const float* bias  = (const float*)d_in[8];
    float* out = (float*)d_out;

    // ws (~23 MB): Kbuf(fp32) | {Kpart bf16 alias Pp} | P | wgt(bf16)
    const size_t KBUF_F = (size_t)BATCH * HWPX * NK;          // 1,605,632 f
    const size_t PP_F   = (size_t)BATCH * NSLAB * CH * NK;    // 3,670,016 f

    float* ws    = (float*)d_ws;
    float* Kbuf  = ws;
    unsigned short* Kpart = (unsigned short*)(ws + KBUF_F);
    float* Pp    = ws + KBUF_F;                 // alias over Kpart
    float* P     = ws + KBUF_F + PP_F;
    unsigned short* wgt = (unsigned short*)(P + (size_t)BATCH * CH * NK);

    kkvec<<<dim3(NSUB * BATCH * 49), dim3(64),  0, stream>>>(x, gamma, beta, mean, var, kw, Kpart);
    ksum <<<dim3(1568),              dim3(256), 0, stream>>>(Kpart, Kbuf);
    kpmat<<<dim3(BATCH * NSLAB),     dim3(256), 0, stream>>>(x, gamma, beta, mean, var, Kbuf, Pp);
    kpred<<<dim3(512),               dim3(256), 0, stream>>>(Pp, P);
    ksoft<<<dim3(BATCH * 8),         dim3(256), 0, stream>>>(P, qw, bank, wgt);
    kconv<<<dim3(BATCH * CH / 4),    dim3(256), 0, stream>>>(x, wgt, bias, out);
}

// Round 21
// 124.075 us; speedup vs baseline: 1.2563x; 1.2563x over previous
//
#include <hip/hip_runtime.h>
#include <hip/hip_bf16.h>

#define BATCH 32
#define CH    256
#define HWPX  3136   // 56*56
#define WIDTH 56
#define NK    16
#define NSLAB 28     // kpmat pixel slabs per batch (112 px each)
#define NSUB  4      // kkvec channel split
#define WGTS  52     // wgt row stride (49 padded to 13*float4)
#define EPSV  1e-5f

__device__ __forceinline__ unsigned pk_bf2(float a, float b) {
    __hip_bfloat16 ha = __float2bfloat16(a), hb = __float2bfloat16(b);
    unsigned short ua = *reinterpret_cast<unsigned short*>(&ha);
    unsigned short ub = *reinterpret_cast<unsigned short*>(&hb);
    return ((unsigned)ub << 16) | ua;
}
__device__ __forceinline__ float up_lo(unsigned v) { return __uint_as_float(v << 16); }
__device__ __forceinline__ float up_hi(unsigned v) { return __uint_as_float(v & 0xffff0000u); }

// ---------------------------------------------------------------------------
// Kernel 1: K-partials (R14 body + bf16 Kpart, proven 55us/R19; R17/18/20
// restructures all lost — kkvec frozen at this plateau).
// ---------------------------------------------------------------------------
__global__ __launch_bounds__(64) void kkvec(
    const float* __restrict__ x,
    const float* __restrict__ gamma, const float* __restrict__ beta,
    const float* __restrict__ mean,  const float* __restrict__ var,
    const float* __restrict__ kw,    unsigned short* __restrict__ Kpart)
{
    const int sub = blockIdx.x / 784;           // 0..3, block-uniform
    const int pb  = blockIdx.x % 784;
    const int job = pb * 64 + threadIdx.x;      // 0..50175 = b*1568 + px2
    const int b   = job / 1568;
    const int px2 = job % 1568;                 // float2 index in plane
    const int cbase = sub * 64;
    const float* xp = x + ((size_t)b * CH + cbase) * HWPX + px2 * 2;

    float acc0[NK], acc1[NK];
#pragma unroll
    for (int k = 0; k < NK; ++k) { acc0[k] = 0.f; acc1[k] = 0.f; }

    for (int c0 = 0; c0 < 64; c0 += 8) {
        float2 v[8];
#pragma unroll
        for (int i = 0; i < 8; ++i)             // 8 x 512B wave-loads in flight
            v[i] = *(const float2*)(xp + (size_t)(c0 + i) * HWPX);
#pragma unroll
        for (int i = 0; i < 8; ++i) {           // BN (params wave-uniform)
            const int c = cbase + c0 + i;
            const float sc = gamma[c] * rsqrtf(var[c] + EPSV);
            const float sh = fmaf(-mean[c], sc, beta[c]);
            v[i].x = fmaf(v[i].x, sc, sh);
            v[i].y = fmaf(v[i].y, sc, sh);
        }
#pragma unroll
        for (int k = 0; k < NK; ++k) {
            const float4 w0 = *(const float4*)(kw + k * CH + cbase + c0);     // uniform
            const float4 w1 = *(const float4*)(kw + k * CH + cbase + c0 + 4); // uniform
            acc0[k] = fmaf(v[0].x, w0.x, acc0[k]); acc1[k] = fmaf(v[0].y, w0.x, acc1[k]);
            acc0[k] = fmaf(v[1].x, w0.y, acc0[k]); acc1[k] = fmaf(v[1].y, w0.y, acc1[k]);
            acc0[k] = fmaf(v[2].x, w0.z, acc0[k]); acc1[k] = fmaf(v[2].y, w0.z, acc1[k]);
            acc0[k] = fmaf(v[3].x, w0.w, acc0[k]); acc1[k] = fmaf(v[3].y, w0.w, acc1[k]);
            acc0[k] = fmaf(v[4].x, w1.x, acc0[k]); acc1[k] = fmaf(v[4].y, w1.x, acc1[k]);
            acc0[k] = fmaf(v[5].x, w1.y, acc0[k]); acc1[k] = fmaf(v[5].y, w1.y, acc1[k]);
            acc0[k] = fmaf(v[6].x, w1.z, acc0[k]); acc1[k] = fmaf(v[6].y, w1.z, acc1[k]);
            acc0[k] = fmaf(v[7].x, w1.w, acc0[k]); acc1[k] = fmaf(v[7].y, w1.w, acc1[k]);
        }
    }

    unsigned short* op = Kpart + ((size_t)sub * BATCH * HWPX + (size_t)b * HWPX + px2 * 2) * NK;
    uint4* op4 = (uint4*)op;
    op4[0] = make_uint4(pk_bf2(acc0[0],  acc0[1]),  pk_bf2(acc0[2],  acc0[3]),
                        pk_bf2(acc0[4],  acc0[5]),  pk_bf2(acc0[6],  acc0[7]));
    op4[1] = make_uint4(pk_bf2(acc0[8],  acc0[9]),  pk_bf2(acc0[10], acc0[11]),
                        pk_bf2(acc0[12], acc0[13]), pk_bf2(acc0[14], acc0[15]));
    op4[2] = make_uint4(pk_bf2(acc1[0],  acc1[1]),  pk_bf2(acc1[2],  acc1[3]),
                        pk_bf2(acc1[4],  acc1[5]),  pk_bf2(acc1[6],  acc1[7]));
    op4[3] = make_uint4(pk_bf2(acc1[8],  acc1[9]),  pk_bf2(acc1[10], acc1[11]),
                        pk_bf2(acc1[12], acc1[13]), pk_bf2(acc1[14], acc1[15]));
}

// ---------------------------------------------------------------------------
// Kernel 1b: Kbuf(fp32) = sum of 4 bf16 Kpart planes (unpack = exact <<16).
// ---------------------------------------------------------------------------
__global__ __launch_bounds__(256) void ksum(
    const unsigned short* __restrict__ Kpart, float* __restrict__ Kbuf)
{
    const int i = blockIdx.x * 256 + threadIdx.x;   // 0..401407 float4 jobs
    const uint2* p = (const uint2*)Kpart;           // 4 bf16 per uint2
    float4 s = make_float4(0.f, 0.f, 0.f, 0.f);
#pragma unroll
    for (int s2 = 0; s2 < NSUB; ++s2) {
        const uint2 v = p[(size_t)s2 * 401408 + i];
        s.x += up_lo(v.x); s.y += up_hi(v.x);
        s.z += up_lo(v.y); s.w += up_hi(v.y);
    }
    ((float4*)Kbuf)[i] = s;
}

// ---------------------------------------------------------------------------
// Kernel 2: P_part[b,nb,c,k] = sum_{n in 112-px slab} BN(x[b,c,n]) * K[b,n,k]
// ---------------------------------------------------------------------------
__global__ __launch_bounds__(256) void kpmat(
    const float* __restrict__ x,
    const float* __restrict__ gamma, const float* __restrict__ beta,
    const float* __restrict__ mean,  const float* __restrict__ var,
    const float* __restrict__ Kbuf,  float* __restrict__ Pp)
{
    const int b  = blockIdx.x / NSLAB;
    const int nb = blockIdx.x % NSLAB;
    const int n0 = nb * 112;
    const int c  = threadIdx.x;

    const float sc = gamma[c] * rsqrtf(var[c] + EPSV);
    const float sh = fmaf(-mean[c], sc, beta[c]);

    const float4* xr = (const float4*)(x + ((size_t)b * CH + c) * HWPX + n0);
    const float*  Kp = Kbuf + ((size_t)b * HWPX + n0) * NK;

    float acc[NK];
#pragma unroll
    for (int k = 0; k < NK; ++k) acc[k] = 0.f;

#pragma unroll 4
    for (int j = 0; j < 28; ++j) {
        const float4 xv = xr[j];
        float v[4];
        v[0] = fmaf(xv.x, sc, sh); v[1] = fmaf(xv.y, sc, sh);
        v[2] = fmaf(xv.z, sc, sh); v[3] = fmaf(xv.w, sc, sh);
#pragma unroll
        for (int d = 0; d < 4; ++d) {
            const float vd = v[d];
#pragma unroll
            for (int kq = 0; kq < 4; ++kq) {
                const float4 kv = *(const float4*)(Kp + ((j*4 + d) * NK) + kq*4); // uniform
                acc[kq*4+0] = fmaf(vd, kv.x, acc[kq*4+0]);
                acc[kq*4+1] = fmaf(vd, kv.y, acc[kq*4+1]);
                acc[kq*4+2] = fmaf(vd, kv.z, acc[kq*4+2]);
                acc[kq*4+3] = fmaf(vd, kv.w, acc[kq*4+3]);
            }
        }
    }
    float4* op = (float4*)(Pp + (((size_t)b * NSLAB + nb) * CH + c) * NK);
#pragma unroll
    for (int kq = 0; kq < 4; ++kq)
        op[kq] = make_float4(acc[kq*4+0], acc[kq*4+1], acc[kq*4+2], acc[kq*4+3]);
}

// ---------------------------------------------------------------------------
// Kernel 2b: reduce slab partials Pp[b][28][CH*NK] -> P[b][CH*NK]
// ---------------------------------------------------------------------------
__global__ __launch_bounds__(256) void kpred(
    const float* __restrict__ Pp, float* __restrict__ P)
{
    const int idx = blockIdx.x * 256 + threadIdx.x;   // 32*4096 total
    const int b = idx >> 12;
    const int e = idx & 4095;
    const float* p = Pp + (size_t)b * NSLAB * 4096 + e;
    float s = 0.f;
#pragma unroll
    for (int nb = 0; nb < NSLAB; ++nb) s += p[(size_t)nb * 4096];
    P[idx] = s;
}

// ---------------------------------------------------------------------------
// Kernel 3: S = q_w @ P; attn = softmax(S/512); wgt = attn @ bank (fp32,
// stride-52 rows -> 13 aligned float4 loads in kconv).
// ---------------------------------------------------------------------------
__global__ __launch_bounds__(256) void ksoft(
    const float* __restrict__ P, const float* __restrict__ qw,
    const float* __restrict__ bank, float* __restrict__ wgt)
{
    const int b  = blockIdx.x >> 3;
    const int cb = blockIdx.x & 7;
    const int tid = threadIdx.x;

    __shared__ float s_P[CH * NK];       // full P[b] (16 KB)
    __shared__ float s_red[32 * 8 * NK]; // partial S (16 KB)
    __shared__ float s_S[32 * NK];
    __shared__ float s_attn[32 * NK];

    for (int idx = tid; idx < CH * NK; idx += 256)
        s_P[idx] = P[(size_t)b * CH * NK + idx];
    __syncthreads();

    const int c_l = tid & 31, sub = tid >> 5;
    const int c = cb * 32 + c_l;
    float a[NK];
#pragma unroll
    for (int k = 0; k < NK; ++k) a[k] = 0.f;
    const float* qrow = qw + (size_t)c * CH + sub * 32;
    for (int j = 0; j < 32; ++j) {
        const float qv = qrow[j];
        const float4* p4 = (const float4*)&s_P[(sub * 32 + j) * NK];
#pragma unroll
        for (int kq = 0; kq < 4; ++kq) {
            const float4 pv = p4[kq];
            a[kq*4+0] = fmaf(qv, pv.x, a[kq*4+0]);
            a[kq*4+1] = fmaf(qv, pv.y, a[kq*4+1]);
            a[kq*4+2] = fmaf(qv, pv.z, a[kq*4+2]);
            a[kq*4+3] = fmaf(qv, pv.w, a[kq*4+3]);
        }
    }
#pragma unroll
    for (int kq = 0; kq < 4; ++kq)
        *(float4*)&s_red[(c_l * 8 + sub) * NK + kq*4] =
            make_float4(a[kq*4+0], a[kq*4+1], a[kq*4+2], a[kq*4+3]);
    __syncthreads();

    for (int idx = tid; idx < 32 * NK; idx += 256) {
        const int cl = idx >> 4, k = idx & 15;
        float s = 0.f;
#pragma unroll
        for (int s2 = 0; s2 < 8; ++s2) s += s_red[(cl * 8 + s2) * NK + k];
        s_S[idx] = s * (1.f / 512.f);
    }
    __syncthreads();

    if (tid < 32) {
        float l[NK];
#pragma unroll
        for (int k = 0; k < NK; ++k) l[k] = s_S[tid * NK + k];
        float m = l[0];
#pragma unroll
        for (int k = 1; k < NK; ++k) m = fmaxf(m, l[k]);
        float sum = 0.f;
#pragma unroll
        for (int k = 0; k < NK; ++k) { l[k] = __expf(l[k] - m); sum += l[k]; }
        const float inv = 1.f / sum;
#pragma unroll
        for (int k = 0; k < NK; ++k) s_attn[tid * NK + k] = l[k] * inv;
    }
    __syncthreads();

    for (int idx = tid; idx < 32 * 49; idx += 256) {
        const int cl = idx / 49, e = idx - cl * 49;
        float wv = 0.f;
#pragma unroll
        for (int k = 0; k < NK; ++k)
            wv = fmaf(s_attn[cl * NK + k], bank[k * 49 + e], wv);
        wgt[((size_t)b * CH + cb * 32 + cl) * WGTS + e] = wv;
    }
}

// ---------------------------------------------------------------------------
// Kernel 4: depthwise 7x7 conv — 4x4-TILE zero-LDS shuffle-halo.
// R19 line-buffer: 58us, VGPR 120, occupancy 17.7%, 1.7x redundant FMA
// (2.16G total, 27us VALU floor), grid 1024 (4 blocks/CU supply).
// R21: thread = 4x4 output tile (q=x-strip 0..15/14 valid, tyv=y-tile
// 0..15/14 valid); block = ONE plane (grid 8192 = 32 blocks/CU supply).
// 10 input-row loads/thread (prefetch-1 pipeline), all y-redundant reads
// L1-served (plane 12.5KB < 32KB L1, whole plane in one block). x-halo via
// 16-lane shuffles (wave-internal); edge/idle lanes masked. FMA = 784/thread
// (algorithmic min, -33%). No mod-7 slots; all indices static.
// ---------------------------------------------------------------------------
__global__ __launch_bounds__(256) void kconv(
    const float* __restrict__ x, const float* __restrict__ wgt,
    const float* __restrict__ bias, float* __restrict__ out)
{
    const int t   = threadIdx.x;         // 0..255
    const int q   = t & 15;              // x strip (14 valid)
    const int tyv = t >> 4;              // y tile (14 valid)
    const int qc  = q  < 14 ? q  : 13;   // clamps: idle lanes shadow valid ones
    const int tyc = tyv < 14 ? tyv : 13;
    const int plane = blockIdx.x;
    const bool qlo = (q == 0), qhi = (q >= 13);
    const float bv = bias[plane & 255];

    float4 wv[13];
    const float4* wp4 = (const float4*)(wgt + (size_t)plane * WGTS);
#pragma unroll
    for (int i = 0; i < 13; ++i) wv[i] = wp4[i];
#define WTAP(idx) ((idx)%4==0 ? wv[(idx)/4].x : (idx)%4==1 ? wv[(idx)/4].y : \
                   (idx)%4==2 ? wv[(idx)/4].z : wv[(idx)/4].w)

    const float* xrow = x   + (size_t)plane * HWPX + 4 * qc;
    float*       orow = out + (size_t)plane * HWPX + 4 * qc;

    float acc[4][4];
#pragma unroll
    for (int iy = 0; iy < 4; ++iy)
#pragma unroll
        for (int ix = 0; ix < 4; ++ix) acc[iy][ix] = bv;

    const int r0 = tyc * 4 - 3;          // first input row (may be <0)
    const float4 z4 = make_float4(0.f, 0.f, 0.f, 0.f);
    float4 vc = (r0 >= 0) ? *(const float4*)(xrow + r0 * WIDTH) : z4;

#pragma unroll
    for (int ir = 0; ir < 10; ++ir) {    // input rows r0..r0+9
        // prefetch next row (rows r0+1..r0+9; r<56 check only needed high end)
        const int rn = r0 + ir + 1;
        float4 vn = (ir < 9 && rn >= 0 && rn < 56)
                        ? *(const float4*)(xrow + rn * WIDTH) : z4;

        // x-halo via shuffles (16-lane groups wave-internal)
        float rr1 = __shfl_up(vc.y, 1), rr2 = __shfl_up(vc.z, 1), rr3 = __shfl_up(vc.w, 1);
        float rr8 = __shfl_down(vc.x, 1), rr9 = __shfl_down(vc.y, 1), rr10 = __shfl_down(vc.z, 1);
        float rr[11];
        rr[1] = qlo ? 0.f : rr1;  rr[2] = qlo ? 0.f : rr2;  rr[3] = qlo ? 0.f : rr3;
        rr[4] = vc.x; rr[5] = vc.y; rr[6] = vc.z; rr[7] = vc.w;
        rr[8] = qhi ? 0.f : rr8;  rr[9] = qhi ? 0.f : rr9;  rr[10] = qhi ? 0.f : rr10;

        // input row ir feeds output iy where ky = ir - iy in [0,6]
#pragma unroll
        for (int iy = 0; iy < 4; ++iy) {
            const int ky = ir - iy;
            if (ky < 0 || ky > 6) continue;       // compile-time pruned
#pragma unroll
            for (int kx = 0; kx < 7; ++kx) {
                const float wk = WTAP(ky * 7 + kx);
#pragma unroll
                for (int ix = 0; ix < 4; ++ix)
                    acc[iy][ix] = fmaf(wk, rr[ix + kx + 1], acc[iy][ix]);
            }
        }
        vc = vn;
    }

    if (q < 14 && tyv < 14) {
#pragma unroll
        for (int iy = 0; iy < 4; ++iy) {
            const int o = tyc * 4 + iy;
            *(float4*)(orow + o * WIDTH) =
                make_float4(acc[iy][0], acc[iy][1], acc[iy][2], acc[iy][3]);
        }
    }
#undef WTAP
}

// ---------------------------------------------------------------------------
extern "C" void kernel_launch(void* const* d_in, const int* in_sizes, int n_in,
                              void* d_out, int out_size, void* d_ws, size_t ws_size,
                              hipStream_t stream)
{
    const float* x     = (const float*)d_in[0];
    const float* gamma = (const float*)d_in[1];
    const float* beta  = (const float*)d_in[2];
    const float* mean  = (const float*)d_in[3];
    const float* var   = (const float*)d_in[4];
    const float* qw    = (const float*)d_in[5];
    const float* kw    = (const float*)d_in[6];
    const float* bank  = (const float*)d_in[7];
    const float* bias  = (const float*)d_in[8];
    float* out = (float*)d_out;

    // ws (~23.3 MB): Kbuf(fp32) | {Kpart bf16 alias Pp} | P | wgt(fp32)
    const size_t KBUF_F = (size_t)BATCH * HWPX * NK;          // 1,605,632 f
    const size_t PP_F   = (size_t)BATCH * NSLAB * CH * NK;    // 3,670,016 f

    float* ws    = (float*)d_ws;
    float* Kbuf  = ws;
    unsigned short* Kpart = (unsigned short*)(ws + KBUF_F);
    float* Pp    = ws + KBUF_F;                 // alias over Kpart
    float* P     = ws + KBUF_F + PP_F;
    float* wgt   = P + (size_t)BATCH * CH * NK;

    kkvec<<<dim3(NSUB * 784),   dim3(64),  0, stream>>>(x, gamma, beta, mean, var, kw, Kpart);
    ksum <<<dim3(1568),         dim3(256), 0, stream>>>(Kpart, Kbuf);
    kpmat<<<dim3(BATCH * NSLAB),dim3(256), 0, stream>>>(x, gamma, beta, mean, var, Kbuf, Pp);
    kpred<<<dim3(512),          dim3(256), 0, stream>>>(Pp, P);
    ksoft<<<dim3(BATCH * 8),    dim3(256), 0, stream>>>(P, qw, bank, wgt);
    kconv<<<dim3(BATCH * CH),   dim3(256), 0, stream>>>(x, wgt, bias, out);
}